// Round 6
// baseline (223.500 us; speedup 1.0000x reference)
//
#include <hip/hip_runtime.h>
#include <hip/hip_bf16.h>
#include <math.h>

// Tucker MoE: T=1024, D=1024, DFF=1024, R=64, G=8, E=32, NEXP=256, K=8, F=8192
// Round 15: revert the r12-r14 router-into-MFMA fusion (D2 was a 57us
// latency-bound long pole; fusion never beat r11's split). Restore r11's
// decomposition, keep the ticket-fused scan (-1 dispatch vs r11):
//  - D1 = prep (896 blk) + router logits split-K (512 blk, r11 code,
//    lp[z][t][e] partials, LKZ=4) -- logits hide under prep occupancy.
//  - D2 = topk (256 blk, b<256, ticket-scan in last block) + pre MFMA (512).
//  - D3..D6 unchanged from r14; off-consumers get clamp guards (42ms
//    profiling artifact insurance).
// 6 dispatches:
//  D1 k_prep_logits : casts/transposes + cnt/tickets/Y zero || router logits
//  D2 k_pre_topk    : topk+scan (256 blk) || pre MFMA (512 blk)
//  D3 k_core_gu     : per-expert gate/up core (LDS, fp32) -> xgb/xub[p]
//  D4 k_fused_ad    : act(gate/up MFMA + silu*mul in LDS) fused w/ down MFMA
//  D5 k_down_core   : per-expert fold xdp + down core + wsm -> atomic Y fp32
//  D6 k_fin         : dense out = Y[1024,512] @ Uod2[512,1024] (bf16 MFMA)

#define T_ 1024
#define D_ 1024
#define DFF_ 1024
#define R_ 64
#define G_ 8
#define E_ 32
#define NEXP_ 256
#define K_ 8
#define F_ 8192
#define LKZ_ 4   // router split-K (chunks of 256)
#define LTB_ 8   // router tokens per block
#define PKZ_ 2   // k_pre split-K
#define DKZ_ 4   // down split-K (chunks of 256 over DFF)
#define LP_ 72   // LDS tile pitch in bf16 elems (16B rows, 2-way bank alias = free)

typedef short bf16x8 __attribute__((ext_vector_type(8)));
typedef float f32x4 __attribute__((ext_vector_type(4)));

__device__ __forceinline__ unsigned short f2bf(float f) {
  unsigned int u = __float_as_uint(f);
  u += 0x7fffu + ((u >> 16) & 1u);  // RNE (finite inputs)
  return (unsigned short)(u >> 16);
}

__device__ __forceinline__ void stage_tile(short* dst, const unsigned short* src,
                                           int gp, int tid) {
  for (int idx = tid; idx < 512; idx += 256) {
    int r = idx >> 3, c8 = (idx & 7) << 3;
    *(uint4*)&dst[r * LP_ + c8] = *(const uint4*)&src[(size_t)r * gp + c8];
  }
}

__device__ __forceinline__ void stage_tile_guard(short* dst, const unsigned short* src,
                                                 int gp, int rows_valid, int tid) {
  for (int idx = tid; idx < 512; idx += 256) {
    int r = idx >> 3, c8 = (idx & 7) << 3;
    uint4 v = make_uint4(0u, 0u, 0u, 0u);
    if (r < rows_valid) v = *(const uint4*)&src[(size_t)r * gp + c8];
    *(uint4*)&dst[r * LP_ + c8] = v;
  }
}

// Stage a 64x64 bf16 tile from an fp32 source (convert on the fly).
__device__ __forceinline__ void stage_tile_f32(short* dst, const float* src,
                                               int gp, int tid) {
  for (int idx = tid; idx < 512; idx += 256) {
    int r = idx >> 3, c8 = (idx & 7) << 3;
    const float* s = &src[(size_t)r * gp + c8];
    float4 v0 = *(const float4*)s;
    float4 v1 = *(const float4*)(s + 4);
    uint4 u;
    u.x = ((unsigned)f2bf(v0.y) << 16) | f2bf(v0.x);
    u.y = ((unsigned)f2bf(v0.w) << 16) | f2bf(v0.z);
    u.z = ((unsigned)f2bf(v1.y) << 16) | f2bf(v1.x);
    u.w = ((unsigned)f2bf(v1.w) << 16) | f2bf(v1.z);
    *(uint4*)&dst[r * LP_ + c8] = u;
  }
}

// Wave computes a 16x64 strip (rows [ms,ms+16)) over K=64 from LDS tiles
// As (rows=m, k-contig) and Bs (rows=n, k-contig; i.e. B^T).
__device__ __forceinline__ void mma_strip(const short* As, const short* Bs,
                                          int ms, int lane, f32x4* acc) {
  int lm = lane & 15;
  int lk = (lane >> 4) << 3;
#pragma unroll
  for (int kc = 0; kc < 64; kc += 32) {
    bf16x8 a = *(const bf16x8*)&As[(ms + lm) * LP_ + kc + lk];
#pragma unroll
    for (int nt = 0; nt < 4; ++nt) {
      bf16x8 b = *(const bf16x8*)&Bs[(nt * 16 + lm) * LP_ + kc + lk];
      acc[nt] = __builtin_amdgcn_mfma_f32_16x16x32_bf16(a, b, acc[nt], 0, 0, 0);
    }
  }
}

// ---------------------------------------------------------------- D1: prep || logits
// 1408 blocks: b<512 = router logits split-K (lp[z][t][e], LKZ=4 chunks of
// 256); b>=512 = prep roles (id=(b-512)>>7: 0..4 cast+T, 5 = uout_down ->
// Uod2T, 6 = x cast + cnt/tickets zero + Y zero).
__global__ __launch_bounds__(256) void k_prep_logits(
    const float* __restrict__ x, const float* __restrict__ Wg,
    const float* __restrict__ s0, const float* __restrict__ s1,
    const float* __restrict__ s2, const float* __restrict__ s3,
    const float* __restrict__ s4, const float* __restrict__ s5,
    unsigned short* __restrict__ xb,
    unsigned short* __restrict__ d0, unsigned short* __restrict__ d1,
    unsigned short* __restrict__ d2, unsigned short* __restrict__ d3,
    unsigned short* __restrict__ d4, unsigned short* __restrict__ d5,
    int* __restrict__ cnt, int* __restrict__ tickets, float* __restrict__ Yf,
    float* __restrict__ lp) {
  __shared__ float shbuf[64 * 65];  // prep: ts[64][65]; logits: xs[8][256]
  int b = blockIdx.x;
  if (b < 512) {
    // ---- router logits: lp[z][t][e], 8 tokens/block, K-chunk of 256
    int t0 = (b & 127) * LTB_;
    int z = b >> 7;
    int e = threadIdx.x;
    float* xs = shbuf;  // [8][256]
    float a[LTB_] = {};
    int dc = z * 256;
    {
      int idx = threadIdx.x * 8;  // 256 thr x 2 float4 = the whole 8x256 tile
      int tl = idx >> 8, d = idx & 255;
      *(float4*)&xs[tl * 256 + d] = *(const float4*)&x[(size_t)(t0 + tl) * D_ + dc + d];
      *(float4*)&xs[tl * 256 + d + 4] = *(const float4*)&x[(size_t)(t0 + tl) * D_ + dc + d + 4];
    }
    __syncthreads();
#pragma unroll 2
    for (int d2 = 0; d2 < 256; d2 += 4) {
      float w0 = Wg[(size_t)(dc + d2 + 0) * NEXP_ + e];
      float w1 = Wg[(size_t)(dc + d2 + 1) * NEXP_ + e];
      float w2 = Wg[(size_t)(dc + d2 + 2) * NEXP_ + e];
      float w3 = Wg[(size_t)(dc + d2 + 3) * NEXP_ + e];
#pragma unroll
      for (int j = 0; j < LTB_; ++j) {
        float4 xv = *(const float4*)&xs[j * 256 + d2];  // broadcast ds_read_b128
        float aj = a[j];
        aj = fmaf(xv.x, w0, aj);
        aj = fmaf(xv.y, w1, aj);
        aj = fmaf(xv.z, w2, aj);
        aj = fmaf(xv.w, w3, aj);
        a[j] = aj;
      }
    }
    size_t base = (size_t)z * T_ * NEXP_;
#pragma unroll
    for (int j = 0; j < LTB_; ++j)
      lp[base + (size_t)(t0 + j) * NEXP_ + e] = a[j];
    return;
  }
  int b2 = b - 512;
  int id = b2 >> 7, rem = b2 & 127, g = rem >> 4, tile = rem & 15;
  if (id == 6) {
    size_t base = ((size_t)g * 16 + tile) * 8192;
    for (int i = threadIdx.x; i < 2048; i += 256) {
      size_t idx = base + (size_t)i * 4;
      float4 v = *(const float4*)&x[idx];
      xb[idx + 0] = f2bf(v.x);
      xb[idx + 1] = f2bf(v.y);
      xb[idx + 2] = f2bf(v.z);
      xb[idx + 3] = f2bf(v.w);
    }
    // zero Y: 128 blocks x 4096 floats = 1024x512
    size_t ybase = ((size_t)g * 16 + tile) * 4096;
    float4 z4 = make_float4(0.f, 0.f, 0.f, 0.f);
    for (int i = threadIdx.x; i < 1024; i += 256)
      *(float4*)&Yf[ybase + (size_t)i * 4] = z4;
    if (g == 0 && tile == 0) {
      cnt[threadIdx.x] = 0;
      if (threadIdx.x == 0) tickets[0] = 0;
    }
    return;
  }
  const float* src = id == 0 ? s0 : id == 1 ? s1 : id == 2 ? s2 : id == 3 ? s3 : id == 4 ? s4 : s5;
  unsigned short* dst = id == 0 ? d0 : id == 1 ? d1 : id == 2 ? d2 : id == 3 ? d3 : id == 4 ? d4 : d5;
  if (id < 3) {
    // uin*: src [g][1024][64] -> dst [g][64][1024]
    int r0 = tile * 64;
    for (int idx = threadIdx.x; idx < 4096; idx += 256) {
      int r = idx >> 6, c = idx & 63;
      shbuf[r * 65 + c] = src[((size_t)g * 1024 + r0 + r) * 64 + c];
    }
    __syncthreads();
    for (int idx = threadIdx.x; idx < 4096; idx += 256) {
      int c = idx >> 6, r = idx & 63;
      dst[((size_t)g * 64 + c) * 1024 + r0 + r] = f2bf(shbuf[r * 65 + c]);
    }
  } else {
    // uout*: src [g][64][1024]; id 3/4 -> [g][1024][64]; id 5 -> [d][g*64+r]
    int c0 = tile * 64;
    for (int idx = threadIdx.x; idx < 4096; idx += 256) {
      int r = idx >> 6, c = idx & 63;
      shbuf[r * 65 + c] = src[((size_t)g * 64 + r) * 1024 + c0 + c];
    }
    __syncthreads();
    if (id == 5) {
      for (int idx = threadIdx.x; idx < 4096; idx += 256) {
        int c = idx >> 6, r = idx & 63;
        dst[(size_t)(c0 + c) * 512 + g * 64 + r] = f2bf(shbuf[r * 65 + c]);
      }
    } else {
      for (int idx = threadIdx.x; idx < 4096; idx += 256) {
        int c = idx >> 6, r = idx & 63;
        dst[((size_t)g * 1024 + c0 + c) * 64 + r] = f2bf(shbuf[r * 65 + c]);
      }
    }
  }
}

// ---------------------------------------------------------------- D2: topk+scan || pre MFMA
// Grid 768: b<256 = topk blocks (4 tokens each, wave per token; fold lp
// partials on load; LAST topk block [ticket] scans cnt->off).
// b>=256 = 512 pre-MFMA blocks.
__global__ __launch_bounds__(256) void k_pre_topk(
    const unsigned short* __restrict__ xb,
    const unsigned short* __restrict__ uinT_g, const unsigned short* __restrict__ uinT_u,
    const float* __restrict__ lp,
    float* __restrict__ Pgp, float* __restrict__ Pup,
    float* __restrict__ wsm, int* __restrict__ bucket, int* __restrict__ cnt,
    int* __restrict__ tickets, int* __restrict__ off) {
  __shared__ short sh2[2 * 64 * LP_];
  __shared__ int lastfl;
  int b = blockIdx.x;
  int tid = threadIdx.x;
  if (b >= 256) {
    int b2 = b - 256;
    int tile = b2 & 15, g = (b2 >> 4) & 7, zz = b2 >> 7;
    int gu = zz >> 1, kz = zz & 1;
    const unsigned short* U = gu ? uinT_u : uinT_g;  // [G][64(r)][1024(d)]
    float* P = gu ? Pup : Pgp;
    int t0 = tile * 64;
    short* As = sh2;
    short* Bs = sh2 + 64 * LP_;
    int lane = tid & 63, ms = (tid >> 6) * 16;
    f32x4 acc[4] = {};
    int dlo = kz * (D_ / PKZ_);
    for (int dc = dlo; dc < dlo + D_ / PKZ_; dc += 64) {
      stage_tile(As, xb + (size_t)t0 * D_ + dc, D_, tid);
      stage_tile(Bs, U + (size_t)g * 64 * 1024 + dc, 1024, tid);
      __syncthreads();
      mma_strip(As, Bs, ms, lane, acc);
      __syncthreads();
    }
    int lm = lane & 15, lq = (lane >> 4) * 4;
#pragma unroll
    for (int nt = 0; nt < 4; ++nt)
#pragma unroll
      for (int r = 0; r < 4; ++r)
        P[((size_t)(kz * G_ + g) * T_ + t0 + ms + lq + r) * R_ + nt * 16 + lm] = acc[nt][r];
    return;
  }
  // ---- topk: one wave per token, folds the LKZ_ logits partials on load
  int wave = tid >> 6;
  int lane = tid & 63;
  int t = b * 4 + wave;
  float v[4];
  int idx[4];
#pragma unroll
  for (int j = 0; j < 4; ++j) {
    idx[j] = lane + 64 * j;
    float s = 0.f;
#pragma unroll
    for (int z = 0; z < LKZ_; ++z)
      s += lp[(size_t)z * T_ * NEXP_ + (size_t)t * NEXP_ + idx[j]];
    v[j] = s;
  }
  float topv[K_];
  int topi[K_];
#pragma unroll
  for (int k = 0; k < K_; ++k) {
    float bv = v[0];
    int bi = idx[0];
#pragma unroll
    for (int j = 1; j < 4; ++j)
      if (v[j] > bv || (v[j] == bv && idx[j] < bi)) { bv = v[j]; bi = idx[j]; }
#pragma unroll
    for (int o2 = 32; o2 > 0; o2 >>= 1) {
      float ov = __shfl_xor(bv, o2);
      int oi = __shfl_xor(bi, o2);
      if (ov > bv || (ov == bv && oi < bi)) { bv = ov; bi = oi; }
    }
    topv[k] = bv;
    topi[k] = bi;
#pragma unroll
    for (int j = 0; j < 4; ++j)
      if (idx[j] == bi) v[j] = -INFINITY;
  }
  float m = topv[0];
  float ev[K_];
  float s = 0.f;
#pragma unroll
  for (int k = 0; k < K_; ++k) { ev[k] = expf(topv[k] - m); s += ev[k]; }
  float inv = 1.f / s;
  if (lane < K_) {
    wsm[t * K_ + lane] = ev[lane] * inv;
    int r1 = atomicAdd(&cnt[topi[lane]], 1);
    bucket[topi[lane] * 1024 + r1] = t * K_ + lane;  // e's rank-ordered f list
  }
  // ---- last topk block scans cnt -> off
  __threadfence();
  __syncthreads();
  if (tid == 0) lastfl = (atomicAdd(&tickets[0], 1) == 255) ? 1 : 0;
  __syncthreads();
  if (lastfl) {
    int* sarr = (int*)sh2;
    int i = tid;
    int c0 = atomicAdd(&cnt[i], 0);  // coherent read of final counts
    sarr[i] = c0;
    __syncthreads();
    for (int d = 1; d < NEXP_; d <<= 1) {
      int vv = (i >= d) ? sarr[i - d] : 0;
      __syncthreads();
      sarr[i] += vv;
      __syncthreads();
    }
    off[i + 1] = sarr[i];
    if (i == 0) off[0] = 0;
  }
}

// ---------------------------------------------------------------- D3: per-expert gate/up core -> xgb/xub[p]
__global__ __launch_bounds__(256) void k_core_gu(const float* __restrict__ Pgp,
                                                 const float* __restrict__ Pup,
                                                 const float* __restrict__ core_g,
                                                 const float* __restrict__ core_u,
                                                 const int* __restrict__ bucket,
                                                 const int* __restrict__ off,
                                                 unsigned short* __restrict__ xgb,
                                                 unsigned short* __restrict__ xub) {
  int e = blockIdx.x >> 1, half = blockIdx.x & 1;
  int g = e >> 5;
  __shared__ float cg[4096], cu[4096];
  __shared__ float rg[4][64], ru[4][64];
  int tid = threadIdx.x;
  for (int i = tid; i < 1024; i += 256) {
    *(float4*)&cg[i * 4] = *(const float4*)&core_g[(size_t)e * 4096 + (size_t)i * 4];
    *(float4*)&cu[i * 4] = *(const float4*)&core_u[(size_t)e * 4096 + (size_t)i * 4];
  }
  int p0 = off[e], n = off[e + 1] - p0;
  if (n < 0) n = 0;
  if (n > 1024) n = 1024;  // guard
  int hn = (n + 1) >> 1;
  int i0 = half * hn;
  int i1 = i0 + hn; if (i1 > n) i1 = n;
  int pl = tid >> 6, o = tid & 63;
  __syncthreads();
  for (int ib = i0; ib < i1; ib += 4) {
    int i = ib + pl;
    bool valid = i < i1;
    int p = p0 + i;
    float sg = 0.f, su = 0.f;
    if (valid) {
      int t = bucket[e * 1024 + i] >> 3;
#pragma unroll
      for (int kz = 0; kz < PKZ_; ++kz) {
        sg += Pgp[((size_t)(kz * G_ + g) * T_ + t) * R_ + o];
        su += Pup[((size_t)(kz * G_ + g) * T_ + t) * R_ + o];
      }
    }
    __syncthreads();
    rg[pl][o] = sg;
    ru[pl][o] = su;
    __syncthreads();
    if (valid) {
      float ag = 0.f, au = 0.f;
#pragma unroll 8
      for (int r = 0; r < R_; ++r) {
        ag = fmaf(rg[pl][r], cg[r * R_ + o], ag);
        au = fmaf(ru[pl][r], cu[r * R_ + o], au);
      }
      xgb[(size_t)p * R_ + o] = f2bf(ag);
      xub[(size_t)p * R_ + o] = f2bf(au);
    }
  }
}

// ---------------------------------------------------------------- D4: fused act+down (MFMA)
__global__ __launch_bounds__(256) void k_fused_ad(const unsigned short* __restrict__ xgb,
                                                  const unsigned short* __restrict__ xub,
                                                  const unsigned short* __restrict__ uoutT_g,
                                                  const unsigned short* __restrict__ uoutT_u,
                                                  const unsigned short* __restrict__ uinT_d,
                                                  const int* __restrict__ off,
                                                  float* __restrict__ xdp) {
  int g = blockIdx.y;
  int kz = blockIdx.z;
  int p0 = off[g * E_];
  int pend = off[g * E_ + E_];
  if (p0 < 0) p0 = 0;
  if (pend > F_) pend = F_;      // guard
  if (pend < p0) pend = p0;
  int ntiles = (pend - p0 + 63) >> 6;
  __shared__ short Ag[64 * LP_], Au[64 * LP_];
  __shared__ short Bg[64 * LP_], Bu[64 * LP_], Bd[64 * LP_];
  __shared__ short Pt[64 * LP_];
  int tid = threadIdx.x, lane = tid & 63, ms = (tid >> 6) * 16;
  int lm = lane & 15, lq = (lane >> 4) * 4;
  for (int tile = blockIdx.x; tile < ntiles; tile += gridDim.x) {
    int pbase = p0 + tile * 64;
    int rv = pend - pbase; if (rv > 64) rv = 64;
    stage_tile_guard(Ag, xgb + (size_t)pbase * R_, R_, rv, tid);
    stage_tile_guard(Au, xub + (size_t)pbase * R_, R_, rv, tid);
    f32x4 accd[4] = {};
#pragma unroll
    for (int c4 = 0; c4 < 4; ++c4) {
      int cc = kz * (DFF_ / DKZ_) + c4 * 64;
      stage_tile(Bg, uoutT_g + ((size_t)g * DFF_ + cc) * R_, R_, tid);
      stage_tile(Bu, uoutT_u + ((size_t)g * DFF_ + cc) * R_, R_, tid);
      stage_tile(Bd, uinT_d + (size_t)g * 64 * 1024 + cc, 1024, tid);
      __syncthreads();
      f32x4 accg[4] = {}, accu[4] = {};
      mma_strip(Ag, Bg, ms, lane, accg);
      mma_strip(Au, Bu, ms, lane, accu);
#pragma unroll
      for (int nt = 0; nt < 4; ++nt)
#pragma unroll
        for (int r = 0; r < 4; ++r) {
          float gv = accg[nt][r];
          float av = gv / (1.f + expf(-gv)) * accu[nt][r];
          Pt[(ms + lq + r) * LP_ + nt * 16 + lm] = (short)f2bf(av);
        }
      mma_strip(Pt, Bd, ms, lane, accd);  // reads only own-wave rows of Pt
      __syncthreads();
    }
#pragma unroll
    for (int nt = 0; nt < 4; ++nt)
#pragma unroll
      for (int r = 0; r < 4; ++r) {
        int p = pbase + ms + lq + r;
        if (p < pend) xdp[((size_t)kz * F_ + p) * R_ + nt * 16 + lm] = accd[nt][r];
      }
    __syncthreads();
  }
}

// ---------------------------------------------------------------- D5: per-expert fold xdp + down core + wsm -> atomic Y
__global__ __launch_bounds__(256) void k_down_core(const float* __restrict__ xdp,
                                                   const float* __restrict__ core_d,
                                                   const int* __restrict__ bucket,
                                                   const float* __restrict__ wsm,
                                                   const int* __restrict__ off,
                                                   float* __restrict__ Yf) {
  int e = blockIdx.x >> 1, half = blockIdx.x & 1;
  int g = e >> 5;
  __shared__ float cd[4096];
  __shared__ float xs[4][64];
  int tid = threadIdx.x;
  for (int i = tid; i < 1024; i += 256)
    *(float4*)&cd[i * 4] = *(const float4*)&core_d[(size_t)e * 4096 + (size_t)i * 4];
  int p0 = off[e], n = off[e + 1] - p0;
  if (n < 0) n = 0;
  if (n > 1024) n = 1024;  // guard
  int hn = (n + 1) >> 1;
  int i0 = half * hn;
  int i1 = i0 + hn; if (i1 > n) i1 = n;
  int pl = tid >> 6, o = tid & 63;
  __syncthreads();
  for (int ib = i0; ib < i1; ib += 4) {
    int i = ib + pl;
    bool valid = i < i1;
    int p = p0 + i;
    int f = valid ? bucket[e * 1024 + i] : 0;
    float s = 0.f;
    if (valid) {
#pragma unroll
      for (int kz = 0; kz < DKZ_; ++kz) s += xdp[((size_t)kz * F_ + p) * R_ + o];
    }
    __syncthreads();
    xs[pl][o] = s;
    __syncthreads();
    if (valid) {
      float a = 0.f;
#pragma unroll 8
      for (int r = 0; r < R_; ++r) a = fmaf(xs[pl][r], cd[r * R_ + o], a);
      atomicAdd(&Yf[(size_t)(f >> 3) * 512 + g * 64 + o], wsm[f] * a);
    }
  }
}

// ---------------------------------------------------------------- D6: out = Y[1024,512] @ Uod2[512,1024], dense MFMA
__global__ __launch_bounds__(256) void k_fin(const float* __restrict__ Yf,
                                             const unsigned short* __restrict__ Uod2T,
                                             float* __restrict__ out) {
  int t0 = blockIdx.x * 64;
  int d0 = blockIdx.y * 64;
  __shared__ short As[64 * LP_], Bs[64 * LP_];
  __shared__ float Os[64 * 68];
  int tid = threadIdx.x, lane = tid & 63, ms = (tid >> 6) * 16;
  int lm = lane & 15, lq = (lane >> 4) * 4;
  f32x4 acc[4] = {};
  for (int kc = 0; kc < 512; kc += 64) {
    stage_tile_f32(As, Yf + (size_t)t0 * 512 + kc, 512, tid);
    stage_tile(Bs, Uod2T + (size_t)d0 * 512 + kc, 512, tid);
    __syncthreads();
    mma_strip(As, Bs, ms, lane, acc);
    __syncthreads();
  }
#pragma unroll
  for (int nt = 0; nt < 4; ++nt)
#pragma unroll
    for (int r = 0; r < 4; ++r)
      Os[(ms + lq + r) * 68 + nt * 16 + lm] = acc[nt][r];
  __syncthreads();
  for (int idx = tid; idx < 1024; idx += 256) {
    int r = idx >> 4, c4 = (idx & 15) << 2;
    *(float4*)&out[(size_t)(t0 + r) * D_ + d0 + c4] = *(const float4*)&Os[r * 68 + c4];
  }
}

// ================================================================ launch
extern "C" void kernel_launch(void* const* d_in, const int* in_sizes, int n_in,
                              void* d_out, int out_size, void* d_ws, size_t ws_size,
                              hipStream_t stream) {
  const float* x = (const float*)d_in[0];
  const float* Wg = (const float*)d_in[1];
  const float* uin_gate = (const float*)d_in[2];
  const float* core_gate = (const float*)d_in[3];
  const float* uout_gate = (const float*)d_in[4];
  const float* uin_up = (const float*)d_in[5];
  const float* core_up = (const float*)d_in[6];
  const float* uout_up = (const float*)d_in[7];
  const float* uin_down = (const float*)d_in[8];
  const float* core_down = (const float*)d_in[9];
  const float* uout_down = (const float*)d_in[10];
  float* out = (float*)d_out;

  char* ws = (char*)d_ws;
  size_t o = 0;
  auto alloc = [&](size_t bytes) { size_t r = o; o = (o + bytes + 255) & ~(size_t)255; return r; };
  size_t o_lp = alloc((size_t)LKZ_ * T_ * NEXP_ * 4);           // 4 MB
  size_t o_wsm = alloc(F_ * 4);
  size_t o_bucket = alloc((size_t)NEXP_ * 1024 * 4);            // 1 MB
  size_t o_cnt = alloc(NEXP_ * 4);
  size_t o_tickets = alloc(256);
  size_t o_off = alloc((NEXP_ + 1) * 4);
  size_t o_xb = alloc((size_t)T_ * D_ * 2);                     // 2 MB
  size_t o_uinT_g = alloc((size_t)G_ * 64 * 1024 * 2);          // 1 MB each
  size_t o_uinT_u = alloc((size_t)G_ * 64 * 1024 * 2);
  size_t o_uinT_d = alloc((size_t)G_ * 64 * 1024 * 2);
  size_t o_uoutT_g = alloc((size_t)G_ * 1024 * 64 * 2);
  size_t o_uoutT_u = alloc((size_t)G_ * 1024 * 64 * 2);
  size_t o_Uod2T = alloc((size_t)D_ * 512 * 2);                 // 1 MB
  size_t o_xgb = alloc((size_t)F_ * R_ * 2);                    // 1 MB
  size_t o_xub = alloc((size_t)F_ * R_ * 2);
  size_t o_Y = alloc((size_t)T_ * 512 * 4);                     // 2 MB fp32
  size_t o_pgp = alloc((size_t)PKZ_ * G_ * T_ * R_ * 4);        // 4 MB
  size_t o_pup = alloc((size_t)PKZ_ * G_ * T_ * R_ * 4);        // 4 MB
  size_t o_xdp = alloc((size_t)DKZ_ * F_ * R_ * 4);             // 8 MB
  (void)ws_size;

  float* lp = (float*)(ws + o_lp);
  float* wsm = (float*)(ws + o_wsm);
  int* bucket = (int*)(ws + o_bucket);
  int* cnt = (int*)(ws + o_cnt);
  int* tickets = (int*)(ws + o_tickets);
  int* off = (int*)(ws + o_off);
  unsigned short* xb = (unsigned short*)(ws + o_xb);
  unsigned short* uinT_g = (unsigned short*)(ws + o_uinT_g);
  unsigned short* uinT_u = (unsigned short*)(ws + o_uinT_u);
  unsigned short* uinT_d = (unsigned short*)(ws + o_uinT_d);
  unsigned short* uoutT_g = (unsigned short*)(ws + o_uoutT_g);
  unsigned short* uoutT_u = (unsigned short*)(ws + o_uoutT_u);
  unsigned short* Uod2T = (unsigned short*)(ws + o_Uod2T);
  unsigned short* xgb = (unsigned short*)(ws + o_xgb);
  unsigned short* xub = (unsigned short*)(ws + o_xub);
  float* Yf = (float*)(ws + o_Y);
  float* pgp = (float*)(ws + o_pgp);
  float* pup = (float*)(ws + o_pup);
  float* xdp = (float*)(ws + o_xdp);

  k_prep_logits<<<1408, 256, 0, stream>>>(x, Wg, uin_gate, uin_up, uin_down,
                                          uout_gate, uout_up, uout_down, xb,
                                          uinT_g, uinT_u, uinT_d,
                                          uoutT_g, uoutT_u, Uod2T,
                                          cnt, tickets, Yf, lp);
  k_pre_topk<<<768, 256, 0, stream>>>(xb, uinT_g, uinT_u, lp, pgp, pup,
                                      wsm, bucket, cnt, tickets, off);
  k_core_gu<<<NEXP_ * 2, 256, 0, stream>>>(pgp, pup, core_gate, core_up, bucket, off, xgb, xub);
  k_fused_ad<<<dim3(16, G_, DKZ_), 256, 0, stream>>>(xgb, xub, uoutT_g, uoutT_u, uinT_d, off, xdp);
  k_down_core<<<NEXP_ * 2, 256, 0, stream>>>(xdp, core_down, bucket, wsm, off, Yf);
  k_fin<<<dim3(16, 16), 256, 0, stream>>>(Yf, Uod2T, out);
}

// Round 7
// 222.733 us; speedup vs baseline: 1.0034x; 1.0034x over previous
//
#include <hip/hip_runtime.h>
#include <hip/hip_bf16.h>
#include <math.h>

// Tucker MoE: T=1024, D=1024, DFF=1024, R=64, G=8, E=32, NEXP=256, K=8, F=8192
// Round 16: async-stage the three barrier-staged MFMA kernels.
//  r15 counters: k_pre_topk=57us, k_fused_ad=60us, both MfmaUtil ~2%,
//  VALUBusy ~12%, Occ ~16-23% -> latency-bound on {reg-stage, barrier, MFMA,
//  barrier} chains at 2-3 blocks/CU. Fix (guide T3-minimal 2-phase +
//  global_load_lds w=16):
//  - LDS tiles linear [64][64] bf16 (gload_lds needs linear dest),
//    double-buffered; prefetch tile i+1 BEFORE computing tile i; one
//    barrier per K-step (implicit vmcnt drain covered by MFMA).
//  - D4 guarded A-tiles: row-clamped gload_lds sources (dup rows; output
//    writes already guarded).
//  - D6 fp32 A-tile: T14 split (loads before MFMA, cvt+ds_write after).
//  All fragment values + MFMA order bit-identical to r15 -> absmax must
//  stay exactly 2.980232e-08 (mapping self-check).
// 6 dispatches: D1 prep||logits, D2 topk+scan||preMFMA, D3 core_gu,
//  D4 fused act+down, D5 down_core->atomic Y, D6 fin GEMM.

#define T_ 1024
#define D_ 1024
#define DFF_ 1024
#define R_ 64
#define G_ 8
#define E_ 32
#define NEXP_ 256
#define K_ 8
#define F_ 8192
#define LKZ_ 4   // router split-K (chunks of 256)
#define LTB_ 8   // router tokens per block
#define PKZ_ 2   // k_pre split-K
#define DKZ_ 4   // down split-K (chunks of 256 over DFF)

typedef short bf16x8 __attribute__((ext_vector_type(8)));
typedef float f32x4 __attribute__((ext_vector_type(4)));

__device__ __forceinline__ unsigned short f2bf(float f) {
  unsigned int u = __float_as_uint(f);
  u += 0x7fffu + ((u >> 16) & 1u);  // RNE (finite inputs)
  return (unsigned short)(u >> 16);
}

// ---- async global->LDS stage of a 64x64 bf16 tile (row-major, pitch 64).
// Wave w covers rows [w*16, w*16+16): 2 issues x 64 lanes x 16B.
// LDS dest is wave-uniform base + lane*16 (HW rule); global src per-lane.
typedef const __attribute__((address_space(1))) unsigned int guint;
typedef __attribute__((address_space(3))) unsigned int luint;

__device__ __forceinline__ void gstage(short* lds, const unsigned short* src,
                                       int gp, int tid) {
  int w = tid >> 6, l = tid & 63;
  int r0 = (w << 4) + (l >> 3);
  int c = (l & 7) << 3;
  __builtin_amdgcn_global_load_lds((guint*)&src[(size_t)r0 * gp + c],
                                   (luint*)&lds[w << 10], 16, 0, 0);
  __builtin_amdgcn_global_load_lds((guint*)&src[(size_t)(r0 + 8) * gp + c],
                                   (luint*)&lds[(w << 10) + 512], 16, 0, 0);
}

// Row-clamped variant: rows >= rows_valid re-read row rows_valid-1 (outputs
// for those rows are discarded by the caller's write guard).
__device__ __forceinline__ void gstage_clamp(short* lds, const unsigned short* src,
                                             int gp, int rows_valid, int tid) {
  int w = tid >> 6, l = tid & 63;
  int c = (l & 7) << 3;
  int r0 = (w << 4) + (l >> 3);
  int r1 = r0 + 8;
  if (r0 >= rows_valid) r0 = rows_valid - 1;
  if (r1 >= rows_valid) r1 = rows_valid - 1;
  __builtin_amdgcn_global_load_lds((guint*)&src[(size_t)r0 * gp + c],
                                   (luint*)&lds[w << 10], 16, 0, 0);
  __builtin_amdgcn_global_load_lds((guint*)&src[(size_t)r1 * gp + c],
                                   (luint*)&lds[(w << 10) + 512], 16, 0, 0);
}

// Wave computes a 16x64 strip (rows [ms,ms+16)) over K=64 from linear LDS
// tiles As (rows=m, k-contig, pitch 64) and Bs (rows=n, k-contig).
__device__ __forceinline__ void mma_strip(const short* As, const short* Bs,
                                          int ms, int lane, f32x4* acc) {
  int lm = lane & 15;
  int lk = (lane >> 4) << 3;
#pragma unroll
  for (int kc = 0; kc < 64; kc += 32) {
    bf16x8 a = *(const bf16x8*)&As[(ms + lm) * 64 + kc + lk];
#pragma unroll
    for (int nt = 0; nt < 4; ++nt) {
      bf16x8 b = *(const bf16x8*)&Bs[(nt * 16 + lm) * 64 + kc + lk];
      acc[nt] = __builtin_amdgcn_mfma_f32_16x16x32_bf16(a, b, acc[nt], 0, 0, 0);
    }
  }
}

// ---- D6 A-tile helpers (T14 split: load f32 early, cvt+ds_write late)
__device__ __forceinline__ void a_load(float4* pre, const float* src, int gp, int tid) {
  int r = tid >> 2, c = (tid & 3) << 4;
  const float* s = &src[(size_t)r * gp + c];
  pre[0] = *(const float4*)(s + 0);
  pre[1] = *(const float4*)(s + 4);
  pre[2] = *(const float4*)(s + 8);
  pre[3] = *(const float4*)(s + 12);
}

__device__ __forceinline__ void a_write(short* dst, const float4* pre, int tid) {
  int r = tid >> 2, c = (tid & 3) << 4;
  uint4 u0, u1;
  u0.x = ((unsigned)f2bf(pre[0].y) << 16) | f2bf(pre[0].x);
  u0.y = ((unsigned)f2bf(pre[0].w) << 16) | f2bf(pre[0].z);
  u0.z = ((unsigned)f2bf(pre[1].y) << 16) | f2bf(pre[1].x);
  u0.w = ((unsigned)f2bf(pre[1].w) << 16) | f2bf(pre[1].z);
  u1.x = ((unsigned)f2bf(pre[2].y) << 16) | f2bf(pre[2].x);
  u1.y = ((unsigned)f2bf(pre[2].w) << 16) | f2bf(pre[2].z);
  u1.z = ((unsigned)f2bf(pre[3].y) << 16) | f2bf(pre[3].x);
  u1.w = ((unsigned)f2bf(pre[3].w) << 16) | f2bf(pre[3].z);
  *(uint4*)&dst[r * 64 + c] = u0;
  *(uint4*)&dst[r * 64 + c + 8] = u1;
}

// ---------------------------------------------------------------- D1: prep || logits
// 1408 blocks: b<512 = router logits split-K (lp[z][t][e], LKZ=4 chunks of
// 256); b>=512 = prep roles (id: 0..4 cast+T, 5 = uout_down -> Uod2T,
// 6 = x cast + cnt/tickets zero + Y zero).
__global__ __launch_bounds__(256) void k_prep_logits(
    const float* __restrict__ x, const float* __restrict__ Wg,
    const float* __restrict__ s0, const float* __restrict__ s1,
    const float* __restrict__ s2, const float* __restrict__ s3,
    const float* __restrict__ s4, const float* __restrict__ s5,
    unsigned short* __restrict__ xb,
    unsigned short* __restrict__ d0, unsigned short* __restrict__ d1,
    unsigned short* __restrict__ d2, unsigned short* __restrict__ d3,
    unsigned short* __restrict__ d4, unsigned short* __restrict__ d5,
    int* __restrict__ cnt, int* __restrict__ tickets, float* __restrict__ Yf,
    float* __restrict__ lp) {
  __shared__ float shbuf[64 * 65];  // prep: ts[64][65]; logits: xs[8][256]
  int b = blockIdx.x;
  if (b < 512) {
    int t0 = (b & 127) * LTB_;
    int z = b >> 7;
    int e = threadIdx.x;
    float* xs = shbuf;  // [8][256]
    float a[LTB_] = {};
    int dc = z * 256;
    {
      int idx = threadIdx.x * 8;
      int tl = idx >> 8, d = idx & 255;
      *(float4*)&xs[tl * 256 + d] = *(const float4*)&x[(size_t)(t0 + tl) * D_ + dc + d];
      *(float4*)&xs[tl * 256 + d + 4] = *(const float4*)&x[(size_t)(t0 + tl) * D_ + dc + d + 4];
    }
    __syncthreads();
#pragma unroll 2
    for (int d2 = 0; d2 < 256; d2 += 4) {
      float w0 = Wg[(size_t)(dc + d2 + 0) * NEXP_ + e];
      float w1 = Wg[(size_t)(dc + d2 + 1) * NEXP_ + e];
      float w2 = Wg[(size_t)(dc + d2 + 2) * NEXP_ + e];
      float w3 = Wg[(size_t)(dc + d2 + 3) * NEXP_ + e];
#pragma unroll
      for (int j = 0; j < LTB_; ++j) {
        float4 xv = *(const float4*)&xs[j * 256 + d2];
        float aj = a[j];
        aj = fmaf(xv.x, w0, aj);
        aj = fmaf(xv.y, w1, aj);
        aj = fmaf(xv.z, w2, aj);
        aj = fmaf(xv.w, w3, aj);
        a[j] = aj;
      }
    }
    size_t base = (size_t)z * T_ * NEXP_;
#pragma unroll
    for (int j = 0; j < LTB_; ++j)
      lp[base + (size_t)(t0 + j) * NEXP_ + e] = a[j];
    return;
  }
  int b2 = b - 512;
  int id = b2 >> 7, rem = b2 & 127, g = rem >> 4, tile = rem & 15;
  if (id == 6) {
    size_t base = ((size_t)g * 16 + tile) * 8192;
    for (int i = threadIdx.x; i < 2048; i += 256) {
      size_t idx = base + (size_t)i * 4;
      float4 v = *(const float4*)&x[idx];
      xb[idx + 0] = f2bf(v.x);
      xb[idx + 1] = f2bf(v.y);
      xb[idx + 2] = f2bf(v.z);
      xb[idx + 3] = f2bf(v.w);
    }
    size_t ybase = ((size_t)g * 16 + tile) * 4096;
    float4 z4 = make_float4(0.f, 0.f, 0.f, 0.f);
    for (int i = threadIdx.x; i < 1024; i += 256)
      *(float4*)&Yf[ybase + (size_t)i * 4] = z4;
    if (g == 0 && tile == 0) {
      cnt[threadIdx.x] = 0;
      if (threadIdx.x == 0) tickets[0] = 0;
    }
    return;
  }
  const float* src = id == 0 ? s0 : id == 1 ? s1 : id == 2 ? s2 : id == 3 ? s3 : id == 4 ? s4 : s5;
  unsigned short* dst = id == 0 ? d0 : id == 1 ? d1 : id == 2 ? d2 : id == 3 ? d3 : id == 4 ? d4 : d5;
  if (id < 3) {
    int r0 = tile * 64;
    for (int idx = threadIdx.x; idx < 4096; idx += 256) {
      int r = idx >> 6, c = idx & 63;
      shbuf[r * 65 + c] = src[((size_t)g * 1024 + r0 + r) * 64 + c];
    }
    __syncthreads();
    for (int idx = threadIdx.x; idx < 4096; idx += 256) {
      int c = idx >> 6, r = idx & 63;
      dst[((size_t)g * 64 + c) * 1024 + r0 + r] = f2bf(shbuf[r * 65 + c]);
    }
  } else {
    int c0 = tile * 64;
    for (int idx = threadIdx.x; idx < 4096; idx += 256) {
      int r = idx >> 6, c = idx & 63;
      shbuf[r * 65 + c] = src[((size_t)g * 64 + r) * 1024 + c0 + c];
    }
    __syncthreads();
    if (id == 5) {
      for (int idx = threadIdx.x; idx < 4096; idx += 256) {
        int c = idx >> 6, r = idx & 63;
        dst[(size_t)(c0 + c) * 512 + g * 64 + r] = f2bf(shbuf[r * 65 + c]);
      }
    } else {
      for (int idx = threadIdx.x; idx < 4096; idx += 256) {
        int c = idx >> 6, r = idx & 63;
        dst[((size_t)g * 1024 + c0 + c) * 64 + r] = f2bf(shbuf[r * 65 + c]);
      }
    }
  }
}

// ---------------------------------------------------------------- D2: topk+scan || pre MFMA
// Grid 768: b<256 = topk (4 tokens, wave/token; ticket-scan in last block);
// b>=256 = 512 pre-MFMA blocks, 2-phase gload_lds double-buffered K loop.
__global__ __launch_bounds__(256) void k_pre_topk(
    const unsigned short* __restrict__ xb,
    const unsigned short* __restrict__ uinT_g, const unsigned short* __restrict__ uinT_u,
    const float* __restrict__ lp,
    float* __restrict__ Pgp, float* __restrict__ Pup,
    float* __restrict__ wsm, int* __restrict__ bucket, int* __restrict__ cnt,
    int* __restrict__ tickets, int* __restrict__ off) {
  __shared__ __align__(16) short sh[4][4096];  // A0 A1 B0 B1 (32 KB)
  __shared__ int lastfl;
  int b = blockIdx.x;
  int tid = threadIdx.x;
  if (b >= 256) {
    int b2 = b - 256;
    int tile = b2 & 15, g = (b2 >> 4) & 7, zz = b2 >> 7;
    int gu = zz >> 1, kz = zz & 1;
    const unsigned short* U = gu ? uinT_u : uinT_g;  // [G][64(r)][1024(d)]
    float* P = gu ? Pup : Pgp;
    int t0 = tile * 64;
    int lane = tid & 63, ms = (tid >> 6) * 16;
    f32x4 acc[4] = {};
    int dlo = kz * (D_ / PKZ_);
    const unsigned short* Asrc = xb + (size_t)t0 * D_;
    const unsigned short* Bsrc = U + (size_t)g * 64 * 1024;
    gstage(sh[0], Asrc + dlo, D_, tid);
    gstage(sh[2], Bsrc + dlo, 1024, tid);
    __syncthreads();
    int cur = 0;
#pragma unroll 1
    for (int i = 0; i < 8; ++i) {
      if (i < 7) {
        int dc = dlo + (i + 1) * 64;
        gstage(sh[cur ^ 1], Asrc + dc, D_, tid);
        gstage(sh[2 + (cur ^ 1)], Bsrc + dc, 1024, tid);
      }
      mma_strip(sh[cur], sh[2 + cur], ms, lane, acc);
      __syncthreads();
      cur ^= 1;
    }
    int lm = lane & 15, lq = (lane >> 4) * 4;
#pragma unroll
    for (int nt = 0; nt < 4; ++nt)
#pragma unroll
      for (int r = 0; r < 4; ++r)
        P[((size_t)(kz * G_ + g) * T_ + t0 + ms + lq + r) * R_ + nt * 16 + lm] = acc[nt][r];
    return;
  }
  // ---- topk: one wave per token, folds the LKZ_ logits partials on load
  int wave = tid >> 6;
  int lane = tid & 63;
  int t = b * 4 + wave;
  float v[4];
  int idx[4];
#pragma unroll
  for (int j = 0; j < 4; ++j) {
    idx[j] = lane + 64 * j;
    float s = 0.f;
#pragma unroll
    for (int z = 0; z < LKZ_; ++z)
      s += lp[(size_t)z * T_ * NEXP_ + (size_t)t * NEXP_ + idx[j]];
    v[j] = s;
  }
  float topv[K_];
  int topi[K_];
#pragma unroll
  for (int k = 0; k < K_; ++k) {
    float bv = v[0];
    int bi = idx[0];
#pragma unroll
    for (int j = 1; j < 4; ++j)
      if (v[j] > bv || (v[j] == bv && idx[j] < bi)) { bv = v[j]; bi = idx[j]; }
#pragma unroll
    for (int o2 = 32; o2 > 0; o2 >>= 1) {
      float ov = __shfl_xor(bv, o2);
      int oi = __shfl_xor(bi, o2);
      if (ov > bv || (ov == bv && oi < bi)) { bv = ov; bi = oi; }
    }
    topv[k] = bv;
    topi[k] = bi;
#pragma unroll
    for (int j = 0; j < 4; ++j)
      if (idx[j] == bi) v[j] = -INFINITY;
  }
  float m = topv[0];
  float ev[K_];
  float s = 0.f;
#pragma unroll
  for (int k = 0; k < K_; ++k) { ev[k] = expf(topv[k] - m); s += ev[k]; }
  float inv = 1.f / s;
  if (lane < K_) {
    wsm[t * K_ + lane] = ev[lane] * inv;
    int r1 = atomicAdd(&cnt[topi[lane]], 1);
    bucket[topi[lane] * 1024 + r1] = t * K_ + lane;
  }
  // ---- last topk block scans cnt -> off
  __threadfence();
  __syncthreads();
  if (tid == 0) lastfl = (atomicAdd(&tickets[0], 1) == 255) ? 1 : 0;
  __syncthreads();
  if (lastfl) {
    int* sarr = (int*)sh;
    int i = tid;
    int c0 = atomicAdd(&cnt[i], 0);
    sarr[i] = c0;
    __syncthreads();
    for (int d = 1; d < NEXP_; d <<= 1) {
      int vv = (i >= d) ? sarr[i - d] : 0;
      __syncthreads();
      sarr[i] += vv;
      __syncthreads();
    }
    off[i + 1] = sarr[i];
    if (i == 0) off[0] = 0;
  }
}

// ---------------------------------------------------------------- D3: per-expert gate/up core -> xgb/xub[p]
__global__ __launch_bounds__(256) void k_core_gu(const float* __restrict__ Pgp,
                                                 const float* __restrict__ Pup,
                                                 const float* __restrict__ core_g,
                                                 const float* __restrict__ core_u,
                                                 const int* __restrict__ bucket,
                                                 const int* __restrict__ off,
                                                 unsigned short* __restrict__ xgb,
                                                 unsigned short* __restrict__ xub) {
  int e = blockIdx.x >> 1, half = blockIdx.x & 1;
  int g = e >> 5;
  __shared__ float cg[4096], cu[4096];
  __shared__ float rg[4][64], ru[4][64];
  int tid = threadIdx.x;
  for (int i = tid; i < 1024; i += 256) {
    *(float4*)&cg[i * 4] = *(const float4*)&core_g[(size_t)e * 4096 + (size_t)i * 4];
    *(float4*)&cu[i * 4] = *(const float4*)&core_u[(size_t)e * 4096 + (size_t)i * 4];
  }
  int p0 = off[e], n = off[e + 1] - p0;
  if (n < 0) n = 0;
  if (n > 1024) n = 1024;
  int hn = (n + 1) >> 1;
  int i0 = half * hn;
  int i1 = i0 + hn; if (i1 > n) i1 = n;
  int pl = tid >> 6, o = tid & 63;
  __syncthreads();
  for (int ib = i0; ib < i1; ib += 4) {
    int i = ib + pl;
    bool valid = i < i1;
    int p = p0 + i;
    float sg = 0.f, su = 0.f;
    if (valid) {
      int t = bucket[e * 1024 + i] >> 3;
#pragma unroll
      for (int kz = 0; kz < PKZ_; ++kz) {
        sg += Pgp[((size_t)(kz * G_ + g) * T_ + t) * R_ + o];
        su += Pup[((size_t)(kz * G_ + g) * T_ + t) * R_ + o];
      }
    }
    __syncthreads();
    rg[pl][o] = sg;
    ru[pl][o] = su;
    __syncthreads();
    if (valid) {
      float ag = 0.f, au = 0.f;
#pragma unroll 8
      for (int r = 0; r < R_; ++r) {
        ag = fmaf(rg[pl][r], cg[r * R_ + o], ag);
        au = fmaf(ru[pl][r], cu[r * R_ + o], au);
      }
      xgb[(size_t)p * R_ + o] = f2bf(ag);
      xub[(size_t)p * R_ + o] = f2bf(au);
    }
  }
}

// ---------------------------------------------------------------- D4: fused act+down (MFMA, 2-phase B prefetch)
__global__ __launch_bounds__(256) void k_fused_ad(const unsigned short* __restrict__ xgb,
                                                  const unsigned short* __restrict__ xub,
                                                  const unsigned short* __restrict__ uoutT_g,
                                                  const unsigned short* __restrict__ uoutT_u,
                                                  const unsigned short* __restrict__ uinT_d,
                                                  const int* __restrict__ off,
                                                  float* __restrict__ xdp) {
  int g = blockIdx.y;
  int kz = blockIdx.z;
  int p0 = off[g * E_];
  int pend = off[g * E_ + E_];
  if (p0 < 0) p0 = 0;
  if (pend > F_) pend = F_;
  if (pend < p0) pend = p0;
  int ntiles = (pend - p0 + 63) >> 6;
  __shared__ __align__(16) short Ag[4096], Au[4096], Pt[4096];
  __shared__ __align__(16) short Bg[2][4096], Bu[2][4096], Bd[2][4096];
  int tid = threadIdx.x, lane = tid & 63, ms = (tid >> 6) * 16;
  int lm = lane & 15, lq = (lane >> 4) * 4;
  int cc0 = kz * (DFF_ / DKZ_);
  const unsigned short* Bgsrc = uoutT_g + (size_t)g * DFF_ * R_;
  const unsigned short* Busrc = uoutT_u + (size_t)g * DFF_ * R_;
  const unsigned short* Bdsrc = uinT_d + (size_t)g * 64 * 1024;
  for (int tile = blockIdx.x; tile < ntiles; tile += gridDim.x) {
    int pbase = p0 + tile * 64;
    int rv = pend - pbase; if (rv > 64) rv = 64;
    gstage_clamp(Ag, xgb + (size_t)pbase * R_, R_, rv, tid);
    gstage_clamp(Au, xub + (size_t)pbase * R_, R_, rv, tid);
    gstage(Bg[0], Bgsrc + (size_t)cc0 * R_, R_, tid);
    gstage(Bu[0], Busrc + (size_t)cc0 * R_, R_, tid);
    gstage(Bd[0], Bdsrc + cc0, 1024, tid);
    __syncthreads();
    f32x4 accd[4] = {};
    int cur = 0;
#pragma unroll 1
    for (int c4 = 0; c4 < 4; ++c4) {
      if (c4 < 3) {
        int cc = cc0 + (c4 + 1) * 64;
        gstage(Bg[cur ^ 1], Bgsrc + (size_t)cc * R_, R_, tid);
        gstage(Bu[cur ^ 1], Busrc + (size_t)cc * R_, R_, tid);
        gstage(Bd[cur ^ 1], Bdsrc + cc, 1024, tid);
      }
      f32x4 accg[4] = {}, accu[4] = {};
      mma_strip(Ag, Bg[cur], ms, lane, accg);
      mma_strip(Au, Bu[cur], ms, lane, accu);
#pragma unroll
      for (int nt = 0; nt < 4; ++nt)
#pragma unroll
        for (int r = 0; r < 4; ++r) {
          float gv = accg[nt][r];
          float av = gv / (1.f + expf(-gv)) * accu[nt][r];
          Pt[(ms + lq + r) * 64 + nt * 16 + lm] = (short)f2bf(av);
        }
      mma_strip(Pt, Bd[cur], ms, lane, accd);  // reads only own-wave rows of Pt
      __syncthreads();
      cur ^= 1;
    }
#pragma unroll
    for (int nt = 0; nt < 4; ++nt)
#pragma unroll
      for (int r = 0; r < 4; ++r) {
        int p = pbase + ms + lq + r;
        if (p < pend) xdp[((size_t)kz * F_ + p) * R_ + nt * 16 + lm] = accd[nt][r];
      }
    __syncthreads();
  }
}

// ---------------------------------------------------------------- D5: per-expert fold xdp + down core + wsm -> atomic Y
__global__ __launch_bounds__(256) void k_down_core(const float* __restrict__ xdp,
                                                   const float* __restrict__ core_d,
                                                   const int* __restrict__ bucket,
                                                   const float* __restrict__ wsm,
                                                   const int* __restrict__ off,
                                                   float* __restrict__ Yf) {
  int e = blockIdx.x >> 1, half = blockIdx.x & 1;
  int g = e >> 5;
  __shared__ float cd[4096];
  __shared__ float xs[4][64];
  int tid = threadIdx.x;
  for (int i = tid; i < 1024; i += 256)
    *(float4*)&cd[i * 4] = *(const float4*)&core_d[(size_t)e * 4096 + (size_t)i * 4];
  int p0 = off[e], n = off[e + 1] - p0;
  if (n < 0) n = 0;
  if (n > 1024) n = 1024;
  int hn = (n + 1) >> 1;
  int i0 = half * hn;
  int i1 = i0 + hn; if (i1 > n) i1 = n;
  int pl = tid >> 6, o = tid & 63;
  __syncthreads();
  for (int ib = i0; ib < i1; ib += 4) {
    int i = ib + pl;
    bool valid = i < i1;
    int p = p0 + i;
    int f = valid ? bucket[e * 1024 + i] : 0;
    float s = 0.f;
    if (valid) {
#pragma unroll
      for (int kz = 0; kz < DKZ_; ++kz) s += xdp[((size_t)kz * F_ + p) * R_ + o];
    }
    __syncthreads();
    xs[pl][o] = s;
    __syncthreads();
    if (valid) {
      float a = 0.f;
#pragma unroll 8
      for (int r = 0; r < R_; ++r) a = fmaf(xs[pl][r], cd[r * R_ + o], a);
      atomicAdd(&Yf[(size_t)(f >> 3) * 512 + g * 64 + o], wsm[f] * a);
    }
  }
}

// ---------------------------------------------------------------- D6: out = Y[1024,512] @ Uod2[512,1024] (2-phase, T14 A-split)
__global__ __launch_bounds__(256) void k_fin(const float* __restrict__ Yf,
                                             const unsigned short* __restrict__ Uod2T,
                                             float* __restrict__ out) {
  int t0 = blockIdx.x * 64;
  int d0 = blockIdx.y * 64;
  __shared__ __align__(16) short sh[4][4096];  // A0 A1 B0 B1; Os overlays after loop
  int tid = threadIdx.x, lane = tid & 63, ms = (tid >> 6) * 16;
  int lm = lane & 15, lq = (lane >> 4) * 4;
  const float* Asrc = Yf + (size_t)t0 * 512;
  const unsigned short* Bsrc = Uod2T + (size_t)d0 * 512;
  f32x4 acc[4] = {};
  {
    float4 pre[4];
    a_load(pre, Asrc, 512, tid);
    a_write(sh[0], pre, tid);
  }
  gstage(sh[2], Bsrc, 512, tid);
  __syncthreads();
  int cur = 0;
#pragma unroll 1
  for (int i = 0; i < 8; ++i) {
    float4 pre[4];
    bool hp = i < 7;
    if (hp) {
      int kc = (i + 1) * 64;
      a_load(pre, Asrc + kc, 512, tid);          // f32 loads issue early
      gstage(sh[2 + (cur ^ 1)], Bsrc + kc, 512, tid);
    }
    mma_strip(sh[cur], sh[2 + cur], ms, lane, acc);
    if (hp) a_write(sh[cur ^ 1], pre, tid);      // cvt+ds_write after MFMA
    __syncthreads();
    cur ^= 1;
  }
  float* Os = (float*)sh;  // 64x68 fp32 = 17.4 KB <= 32 KB
#pragma unroll
  for (int nt = 0; nt < 4; ++nt)
#pragma unroll
    for (int r = 0; r < 4; ++r)
      Os[(ms + lq + r) * 68 + nt * 16 + lm] = acc[nt][r];
  __syncthreads();
  for (int idx = tid; idx < 1024; idx += 256) {
    int r = idx >> 4, c4 = (idx & 15) << 2;
    *(float4*)&out[(size_t)(t0 + r) * D_ + d0 + c4] = *(const float4*)&Os[r * 68 + c4];
  }
}

// ================================================================ launch
extern "C" void kernel_launch(void* const* d_in, const int* in_sizes, int n_in,
                              void* d_out, int out_size, void* d_ws, size_t ws_size,
                              hipStream_t stream) {
  const float* x = (const float*)d_in[0];
  const float* Wg = (const float*)d_in[1];
  const float* uin_gate = (const float*)d_in[2];
  const float* core_gate = (const float*)d_in[3];
  const float* uout_gate = (const float*)d_in[4];
  const float* uin_up = (const float*)d_in[5];
  const float* core_up = (const float*)d_in[6];
  const float* uout_up = (const float*)d_in[7];
  const float* uin_down = (const float*)d_in[8];
  const float* core_down = (const float*)d_in[9];
  const float* uout_down = (const float*)d_in[10];
  float* out = (float*)d_out;

  char* ws = (char*)d_ws;
  size_t o = 0;
  auto alloc = [&](size_t bytes) { size_t r = o; o = (o + bytes + 255) & ~(size_t)255; return r; };
  size_t o_lp = alloc((size_t)LKZ_ * T_ * NEXP_ * 4);           // 4 MB
  size_t o_wsm = alloc(F_ * 4);
  size_t o_bucket = alloc((size_t)NEXP_ * 1024 * 4);            // 1 MB
  size_t o_cnt = alloc(NEXP_ * 4);
  size_t o_tickets = alloc(256);
  size_t o_off = alloc((NEXP_ + 1) * 4);
  size_t o_xb = alloc((size_t)T_ * D_ * 2);                     // 2 MB
  size_t o_uinT_g = alloc((size_t)G_ * 64 * 1024 * 2);          // 1 MB each
  size_t o_uinT_u = alloc((size_t)G_ * 64 * 1024 * 2);
  size_t o_uinT_d = alloc((size_t)G_ * 64 * 1024 * 2);
  size_t o_uoutT_g = alloc((size_t)G_ * 1024 * 64 * 2);
  size_t o_uoutT_u = alloc((size_t)G_ * 1024 * 64 * 2);
  size_t o_Uod2T = alloc((size_t)D_ * 512 * 2);                 // 1 MB
  size_t o_xgb = alloc((size_t)F_ * R_ * 2);                    // 1 MB
  size_t o_xub = alloc((size_t)F_ * R_ * 2);
  size_t o_Y = alloc((size_t)T_ * 512 * 4);                     // 2 MB fp32
  size_t o_pgp = alloc((size_t)PKZ_ * G_ * T_ * R_ * 4);        // 4 MB
  size_t o_pup = alloc((size_t)PKZ_ * G_ * T_ * R_ * 4);        // 4 MB
  size_t o_xdp = alloc((size_t)DKZ_ * F_ * R_ * 4);             // 8 MB
  (void)ws_size;

  float* lp = (float*)(ws + o_lp);
  float* wsm = (float*)(ws + o_wsm);
  int* bucket = (int*)(ws + o_bucket);
  int* cnt = (int*)(ws + o_cnt);
  int* tickets = (int*)(ws + o_tickets);
  int* off = (int*)(ws + o_off);
  unsigned short* xb = (unsigned short*)(ws + o_xb);
  unsigned short* uinT_g = (unsigned short*)(ws + o_uinT_g);
  unsigned short* uinT_u = (unsigned short*)(ws + o_uinT_u);
  unsigned short* uinT_d = (unsigned short*)(ws + o_uinT_d);
  unsigned short* uoutT_g = (unsigned short*)(ws + o_uoutT_g);
  unsigned short* uoutT_u = (unsigned short*)(ws + o_uoutT_u);
  unsigned short* Uod2T = (unsigned short*)(ws + o_Uod2T);
  unsigned short* xgb = (unsigned short*)(ws + o_xgb);
  unsigned short* xub = (unsigned short*)(ws + o_xub);
  float* Yf = (float*)(ws + o_Y);
  float* pgp = (float*)(ws + o_pgp);
  float* pup = (float*)(ws + o_pup);
  float* xdp = (float*)(ws + o_xdp);

  k_prep_logits<<<1408, 256, 0, stream>>>(x, Wg, uin_gate, uin_up, uin_down,
                                          uout_gate, uout_up, uout_down, xb,
                                          uinT_g, uinT_u, uinT_d,
                                          uoutT_g, uoutT_u, Uod2T,
                                          cnt, tickets, Yf, lp);
  k_pre_topk<<<768, 256, 0, stream>>>(xb, uinT_g, uinT_u, lp, pgp, pup,
                                      wsm, bucket, cnt, tickets, off);
  k_core_gu<<<NEXP_ * 2, 256, 0, stream>>>(pgp, pup, core_gate, core_up, bucket, off, xgb, xub);
  k_fused_ad<<<dim3(16, G_, DKZ_), 256, 0, stream>>>(xgb, xub, uoutT_g, uoutT_u, uinT_d, off, xdp);
  k_down_core<<<NEXP_ * 2, 256, 0, stream>>>(xdp, core_down, bucket, wsm, off, Yf);
  k_fin<<<dim3(16, 16), 256, 0, stream>>>(Yf, Uod2T, out);
}

// Round 8
// 210.413 us; speedup vs baseline: 1.0622x; 1.0586x over previous
//
#include <hip/hip_runtime.h>
#include <hip/hip_bf16.h>
#include <math.h>

// Tucker MoE: T=1024, D=1024, DFF=1024, R=64, G=8, E=32, NEXP=256, K=8, F=8192
// Round 17:
//  (a) Fix r16's self-inflicted 16-way LDS bank conflict (SQ_LDS_BANK_CONFLICT
//      655K->1.97M): linear [64][64] bf16 tiles have 128B rows -> lanes 0-15
//      of ds_read_b128 all hit one bank. T2 both-sides XOR swizzle
//      (chunk ^= row&7 on 16B chunks): gload_lds keeps LINEAR dest but the
//      GLOBAL source is pre-swizzled (rule #21); ds_read + Pt writes use the
//      swizzled offset. Placement-only: values/order bit-identical, absmax
//      must stay exactly 2.980232e-08.
//  (b) Split D2 for attribution: k_pre (512 MFMA blocks) + k_topk (256
//      blocks + ticket scan). k_pre_topk has been pinned at 52-57us across
//      4 different stagings -> need to know which half.
// 7 dispatches: D1 prep||logits, D2a pre-MFMA, D2b topk+scan, D3 core_gu,
//  D4 fused act+down, D5 down_core->atomic Y, D6 fin GEMM.

#define T_ 1024
#define D_ 1024
#define DFF_ 1024
#define R_ 64
#define G_ 8
#define E_ 32
#define NEXP_ 256
#define K_ 8
#define F_ 8192
#define LKZ_ 4   // router split-K (chunks of 256)
#define LTB_ 8   // router tokens per block
#define PKZ_ 2   // k_pre split-K
#define DKZ_ 4   // down split-K (chunks of 256 over DFF)

typedef short bf16x8 __attribute__((ext_vector_type(8)));
typedef float f32x4 __attribute__((ext_vector_type(4)));

__device__ __forceinline__ unsigned short f2bf(float f) {
  unsigned int u = __float_as_uint(f);
  u += 0x7fffu + ((u >> 16) & 1u);  // RNE (finite inputs)
  return (unsigned short)(u >> 16);
}

// ---- async global->LDS stage of a 64x64 bf16 tile, st-16x32-style swizzle.
// LDS layout: row r (128B), 16B chunk slot c stores global chunk c^(r&7).
// gload_lds writes linearly (wave base + lane*16) -> lane's slot is
// (row rs = w*16 + l>>3, chunk cs = l&7); it FETCHES global chunk cs^(rs&7).
typedef const __attribute__((address_space(1))) unsigned int guint;
typedef __attribute__((address_space(3))) unsigned int luint;

__device__ __forceinline__ void gstage_swz(short* lds, const unsigned short* src,
                                           int gp, int tid) {
  int w = tid >> 6, l = tid & 63;
  int rs = (w << 4) + (l >> 3);
  int cs = ((l & 7) ^ (rs & 7)) << 3;  // (rs+8)&7 == rs&7
  __builtin_amdgcn_global_load_lds((guint*)&src[(size_t)rs * gp + cs],
                                   (luint*)&lds[w << 10], 16, 0, 0);
  __builtin_amdgcn_global_load_lds((guint*)&src[(size_t)(rs + 8) * gp + cs],
                                   (luint*)&lds[(w << 10) + 512], 16, 0, 0);
}

// Row-clamped variant: slot-row rs keeps ITS swizzle (cs from rs), but the
// fetch row is clamped; garbage rows are finite and write-guarded downstream.
__device__ __forceinline__ void gstage_clamp_swz(short* lds, const unsigned short* src,
                                                 int gp, int rows_valid, int tid) {
  int w = tid >> 6, l = tid & 63;
  int rs = (w << 4) + (l >> 3);
  int cs = ((l & 7) ^ (rs & 7)) << 3;
  int r0 = rs, r1 = rs + 8;
  if (r0 >= rows_valid) r0 = rows_valid - 1;
  if (r1 >= rows_valid) r1 = rows_valid - 1;
  __builtin_amdgcn_global_load_lds((guint*)&src[(size_t)r0 * gp + cs],
                                   (luint*)&lds[w << 10], 16, 0, 0);
  __builtin_amdgcn_global_load_lds((guint*)&src[(size_t)r1 * gp + cs],
                                   (luint*)&lds[(w << 10) + 512], 16, 0, 0);
}

// Wave computes a 16x64 strip (rows [ms,ms+16)) over K=64 from swizzled
// linear LDS tiles (pitch 64). Read offset: row*64 + ((chunk^(row&7))<<3).
__device__ __forceinline__ void mma_strip_swz(const short* As, const short* Bs,
                                              int ms, int lane, f32x4* acc) {
  int lm = lane & 15;
  int lk = (lane >> 4) << 3;
  int x7 = lm & 7;  // row&7 for both A rows (ms+lm) and B rows (nt*16+lm)
#pragma unroll
  for (int kc = 0; kc < 64; kc += 32) {
    int ch = (kc + lk) >> 3;
    int co = ((ch ^ x7) << 3);
    bf16x8 a = *(const bf16x8*)&As[(ms + lm) * 64 + co];
#pragma unroll
    for (int nt = 0; nt < 4; ++nt) {
      bf16x8 b = *(const bf16x8*)&Bs[(nt * 16 + lm) * 64 + co];
      acc[nt] = __builtin_amdgcn_mfma_f32_16x16x32_bf16(a, b, acc[nt], 0, 0, 0);
    }
  }
}

// ---- D6 A-tile helpers (T14 split: load f32 early, cvt+ds_write late, swz)
__device__ __forceinline__ void a_load(float4* pre, const float* src, int gp, int tid) {
  int r = tid >> 2, c = (tid & 3) << 4;
  const float* s = &src[(size_t)r * gp + c];
  pre[0] = *(const float4*)(s + 0);
  pre[1] = *(const float4*)(s + 4);
  pre[2] = *(const float4*)(s + 8);
  pre[3] = *(const float4*)(s + 12);
}

__device__ __forceinline__ void a_write_swz(short* dst, const float4* pre, int tid) {
  int r = tid >> 2;
  int ch0 = (tid & 3) << 1;  // first of two 16B chunks
  uint4 u0, u1;
  u0.x = ((unsigned)f2bf(pre[0].y) << 16) | f2bf(pre[0].x);
  u0.y = ((unsigned)f2bf(pre[0].w) << 16) | f2bf(pre[0].z);
  u0.z = ((unsigned)f2bf(pre[1].y) << 16) | f2bf(pre[1].x);
  u0.w = ((unsigned)f2bf(pre[1].w) << 16) | f2bf(pre[1].z);
  u1.x = ((unsigned)f2bf(pre[2].y) << 16) | f2bf(pre[2].x);
  u1.y = ((unsigned)f2bf(pre[2].w) << 16) | f2bf(pre[2].z);
  u1.z = ((unsigned)f2bf(pre[3].y) << 16) | f2bf(pre[3].x);
  u1.w = ((unsigned)f2bf(pre[3].w) << 16) | f2bf(pre[3].z);
  int r7 = r & 7;
  *(uint4*)&dst[r * 64 + ((ch0 ^ r7) << 3)] = u0;
  *(uint4*)&dst[r * 64 + (((ch0 + 1) ^ r7) << 3)] = u1;
}

// ---------------------------------------------------------------- D1: prep || logits
__global__ __launch_bounds__(256) void k_prep_logits(
    const float* __restrict__ x, const float* __restrict__ Wg,
    const float* __restrict__ s0, const float* __restrict__ s1,
    const float* __restrict__ s2, const float* __restrict__ s3,
    const float* __restrict__ s4, const float* __restrict__ s5,
    unsigned short* __restrict__ xb,
    unsigned short* __restrict__ d0, unsigned short* __restrict__ d1,
    unsigned short* __restrict__ d2, unsigned short* __restrict__ d3,
    unsigned short* __restrict__ d4, unsigned short* __restrict__ d5,
    int* __restrict__ cnt, int* __restrict__ tickets, float* __restrict__ Yf,
    float* __restrict__ lp) {
  __shared__ float shbuf[64 * 65];  // prep: ts[64][65]; logits: xs[8][256]
  int b = blockIdx.x;
  if (b < 512) {
    int t0 = (b & 127) * LTB_;
    int z = b >> 7;
    int e = threadIdx.x;
    float* xs = shbuf;  // [8][256]
    float a[LTB_] = {};
    int dc = z * 256;
    {
      int idx = threadIdx.x * 8;
      int tl = idx >> 8, d = idx & 255;
      *(float4*)&xs[tl * 256 + d] = *(const float4*)&x[(size_t)(t0 + tl) * D_ + dc + d];
      *(float4*)&xs[tl * 256 + d + 4] = *(const float4*)&x[(size_t)(t0 + tl) * D_ + dc + d + 4];
    }
    __syncthreads();
#pragma unroll 2
    for (int d2 = 0; d2 < 256; d2 += 4) {
      float w0 = Wg[(size_t)(dc + d2 + 0) * NEXP_ + e];
      float w1 = Wg[(size_t)(dc + d2 + 1) * NEXP_ + e];
      float w2 = Wg[(size_t)(dc + d2 + 2) * NEXP_ + e];
      float w3 = Wg[(size_t)(dc + d2 + 3) * NEXP_ + e];
#pragma unroll
      for (int j = 0; j < LTB_; ++j) {
        float4 xv = *(const float4*)&xs[j * 256 + d2];
        float aj = a[j];
        aj = fmaf(xv.x, w0, aj);
        aj = fmaf(xv.y, w1, aj);
        aj = fmaf(xv.z, w2, aj);
        aj = fmaf(xv.w, w3, aj);
        a[j] = aj;
      }
    }
    size_t base = (size_t)z * T_ * NEXP_;
#pragma unroll
    for (int j = 0; j < LTB_; ++j)
      lp[base + (size_t)(t0 + j) * NEXP_ + e] = a[j];
    return;
  }
  int b2 = b - 512;
  int id = b2 >> 7, rem = b2 & 127, g = rem >> 4, tile = rem & 15;
  if (id == 6) {
    size_t base = ((size_t)g * 16 + tile) * 8192;
    for (int i = threadIdx.x; i < 2048; i += 256) {
      size_t idx = base + (size_t)i * 4;
      float4 v = *(const float4*)&x[idx];
      xb[idx + 0] = f2bf(v.x);
      xb[idx + 1] = f2bf(v.y);
      xb[idx + 2] = f2bf(v.z);
      xb[idx + 3] = f2bf(v.w);
    }
    size_t ybase = ((size_t)g * 16 + tile) * 4096;
    float4 z4 = make_float4(0.f, 0.f, 0.f, 0.f);
    for (int i = threadIdx.x; i < 1024; i += 256)
      *(float4*)&Yf[ybase + (size_t)i * 4] = z4;
    if (g == 0 && tile == 0) {
      cnt[threadIdx.x] = 0;
      if (threadIdx.x == 0) tickets[0] = 0;
    }
    return;
  }
  const float* src = id == 0 ? s0 : id == 1 ? s1 : id == 2 ? s2 : id == 3 ? s3 : id == 4 ? s4 : s5;
  unsigned short* dst = id == 0 ? d0 : id == 1 ? d1 : id == 2 ? d2 : id == 3 ? d3 : id == 4 ? d4 : d5;
  if (id < 3) {
    int r0 = tile * 64;
    for (int idx = threadIdx.x; idx < 4096; idx += 256) {
      int r = idx >> 6, c = idx & 63;
      shbuf[r * 65 + c] = src[((size_t)g * 1024 + r0 + r) * 64 + c];
    }
    __syncthreads();
    for (int idx = threadIdx.x; idx < 4096; idx += 256) {
      int c = idx >> 6, r = idx & 63;
      dst[((size_t)g * 64 + c) * 1024 + r0 + r] = f2bf(shbuf[r * 65 + c]);
    }
  } else {
    int c0 = tile * 64;
    for (int idx = threadIdx.x; idx < 4096; idx += 256) {
      int r = idx >> 6, c = idx & 63;
      shbuf[r * 65 + c] = src[((size_t)g * 64 + r) * 1024 + c0 + c];
    }
    __syncthreads();
    if (id == 5) {
      for (int idx = threadIdx.x; idx < 4096; idx += 256) {
        int c = idx >> 6, r = idx & 63;
        dst[(size_t)(c0 + c) * 512 + g * 64 + r] = f2bf(shbuf[r * 65 + c]);
      }
    } else {
      for (int idx = threadIdx.x; idx < 4096; idx += 256) {
        int c = idx >> 6, r = idx & 63;
        dst[((size_t)g * 1024 + c0 + c) * 64 + r] = f2bf(shbuf[r * 65 + c]);
      }
    }
  }
}

// ---------------------------------------------------------------- D2a: pre MFMA (512 blocks)
__global__ __launch_bounds__(256) void k_pre(
    const unsigned short* __restrict__ xb,
    const unsigned short* __restrict__ uinT_g, const unsigned short* __restrict__ uinT_u,
    float* __restrict__ Pgp, float* __restrict__ Pup) {
  __shared__ __align__(16) short sh[4][4096];  // A0 A1 B0 B1 (32 KB)
  int b = blockIdx.x;
  int tid = threadIdx.x;
  int tile = b & 15, g = (b >> 4) & 7, zz = b >> 7;
  int gu = zz >> 1, kz = zz & 1;
  const unsigned short* U = gu ? uinT_u : uinT_g;  // [G][64(r)][1024(d)]
  float* P = gu ? Pup : Pgp;
  int t0 = tile * 64;
  int lane = tid & 63, ms = (tid >> 6) * 16;
  f32x4 acc[4] = {};
  int dlo = kz * (D_ / PKZ_);
  const unsigned short* Asrc = xb + (size_t)t0 * D_;
  const unsigned short* Bsrc = U + (size_t)g * 64 * 1024;
  gstage_swz(sh[0], Asrc + dlo, D_, tid);
  gstage_swz(sh[2], Bsrc + dlo, 1024, tid);
  __syncthreads();
  int cur = 0;
#pragma unroll 1
  for (int i = 0; i < 8; ++i) {
    if (i < 7) {
      int dc = dlo + (i + 1) * 64;
      gstage_swz(sh[cur ^ 1], Asrc + dc, D_, tid);
      gstage_swz(sh[2 + (cur ^ 1)], Bsrc + dc, 1024, tid);
    }
    mma_strip_swz(sh[cur], sh[2 + cur], ms, lane, acc);
    __syncthreads();
    cur ^= 1;
  }
  int lm = lane & 15, lq = (lane >> 4) * 4;
#pragma unroll
  for (int nt = 0; nt < 4; ++nt)
#pragma unroll
    for (int r = 0; r < 4; ++r)
      P[((size_t)(kz * G_ + g) * T_ + t0 + ms + lq + r) * R_ + nt * 16 + lm] = acc[nt][r];
}

// ---------------------------------------------------------------- D2b: topk + ticket scan (256 blocks)
__global__ __launch_bounds__(256) void k_topk(
    const float* __restrict__ lp,
    float* __restrict__ wsm, int* __restrict__ bucket, int* __restrict__ cnt,
    int* __restrict__ tickets, int* __restrict__ off) {
  __shared__ int sarr[NEXP_];
  __shared__ int lastfl;
  int b = blockIdx.x;
  int tid = threadIdx.x;
  int wave = tid >> 6;
  int lane = tid & 63;
  int t = b * 4 + wave;
  float v[4];
  int idx[4];
#pragma unroll
  for (int j = 0; j < 4; ++j) {
    idx[j] = lane + 64 * j;
    float s = 0.f;
#pragma unroll
    for (int z = 0; z < LKZ_; ++z)
      s += lp[(size_t)z * T_ * NEXP_ + (size_t)t * NEXP_ + idx[j]];
    v[j] = s;
  }
  float topv[K_];
  int topi[K_];
#pragma unroll
  for (int k = 0; k < K_; ++k) {
    float bv = v[0];
    int bi = idx[0];
#pragma unroll
    for (int j = 1; j < 4; ++j)
      if (v[j] > bv || (v[j] == bv && idx[j] < bi)) { bv = v[j]; bi = idx[j]; }
#pragma unroll
    for (int o2 = 32; o2 > 0; o2 >>= 1) {
      float ov = __shfl_xor(bv, o2);
      int oi = __shfl_xor(bi, o2);
      if (ov > bv || (ov == bv && oi < bi)) { bv = ov; bi = oi; }
    }
    topv[k] = bv;
    topi[k] = bi;
#pragma unroll
    for (int j = 0; j < 4; ++j)
      if (idx[j] == bi) v[j] = -INFINITY;
  }
  float m = topv[0];
  float ev[K_];
  float s = 0.f;
#pragma unroll
  for (int k = 0; k < K_; ++k) { ev[k] = expf(topv[k] - m); s += ev[k]; }
  float inv = 1.f / s;
  if (lane < K_) {
    wsm[t * K_ + lane] = ev[lane] * inv;
    int r1 = atomicAdd(&cnt[topi[lane]], 1);
    bucket[topi[lane] * 1024 + r1] = t * K_ + lane;
  }
  // ---- last block scans cnt -> off
  __threadfence();
  __syncthreads();
  if (tid == 0) lastfl = (atomicAdd(&tickets[0], 1) == 255) ? 1 : 0;
  __syncthreads();
  if (lastfl) {
    int i = tid;
    int c0 = atomicAdd(&cnt[i], 0);
    sarr[i] = c0;
    __syncthreads();
    for (int d = 1; d < NEXP_; d <<= 1) {
      int vv = (i >= d) ? sarr[i - d] : 0;
      __syncthreads();
      sarr[i] += vv;
      __syncthreads();
    }
    off[i + 1] = sarr[i];
    if (i == 0) off[0] = 0;
  }
}

// ---------------------------------------------------------------- D3: per-expert gate/up core -> xgb/xub[p]
__global__ __launch_bounds__(256) void k_core_gu(const float* __restrict__ Pgp,
                                                 const float* __restrict__ Pup,
                                                 const float* __restrict__ core_g,
                                                 const float* __restrict__ core_u,
                                                 const int* __restrict__ bucket,
                                                 const int* __restrict__ off,
                                                 unsigned short* __restrict__ xgb,
                                                 unsigned short* __restrict__ xub) {
  int e = blockIdx.x >> 1, half = blockIdx.x & 1;
  int g = e >> 5;
  __shared__ float cg[4096], cu[4096];
  __shared__ float rg[4][64], ru[4][64];
  int tid = threadIdx.x;
  for (int i = tid; i < 1024; i += 256) {
    *(float4*)&cg[i * 4] = *(const float4*)&core_g[(size_t)e * 4096 + (size_t)i * 4];
    *(float4*)&cu[i * 4] = *(const float4*)&core_u[(size_t)e * 4096 + (size_t)i * 4];
  }
  int p0 = off[e], n = off[e + 1] - p0;
  if (n < 0) n = 0;
  if (n > 1024) n = 1024;
  int hn = (n + 1) >> 1;
  int i0 = half * hn;
  int i1 = i0 + hn; if (i1 > n) i1 = n;
  int pl = tid >> 6, o = tid & 63;
  __syncthreads();
  for (int ib = i0; ib < i1; ib += 4) {
    int i = ib + pl;
    bool valid = i < i1;
    int p = p0 + i;
    float sg = 0.f, su = 0.f;
    if (valid) {
      int t = bucket[e * 1024 + i] >> 3;
#pragma unroll
      for (int kz = 0; kz < PKZ_; ++kz) {
        sg += Pgp[((size_t)(kz * G_ + g) * T_ + t) * R_ + o];
        su += Pup[((size_t)(kz * G_ + g) * T_ + t) * R_ + o];
      }
    }
    __syncthreads();
    rg[pl][o] = sg;
    ru[pl][o] = su;
    __syncthreads();
    if (valid) {
      float ag = 0.f, au = 0.f;
#pragma unroll 8
      for (int r = 0; r < R_; ++r) {
        ag = fmaf(rg[pl][r], cg[r * R_ + o], ag);
        au = fmaf(ru[pl][r], cu[r * R_ + o], au);
      }
      xgb[(size_t)p * R_ + o] = f2bf(ag);
      xub[(size_t)p * R_ + o] = f2bf(au);
    }
  }
}

// ---------------------------------------------------------------- D4: fused act+down (MFMA, 2-phase B prefetch, swz)
__global__ __launch_bounds__(256) void k_fused_ad(const unsigned short* __restrict__ xgb,
                                                  const unsigned short* __restrict__ xub,
                                                  const unsigned short* __restrict__ uoutT_g,
                                                  const unsigned short* __restrict__ uoutT_u,
                                                  const unsigned short* __restrict__ uinT_d,
                                                  const int* __restrict__ off,
                                                  float* __restrict__ xdp) {
  int g = blockIdx.y;
  int kz = blockIdx.z;
  int p0 = off[g * E_];
  int pend = off[g * E_ + E_];
  if (p0 < 0) p0 = 0;
  if (pend > F_) pend = F_;
  if (pend < p0) pend = p0;
  int ntiles = (pend - p0 + 63) >> 6;
  __shared__ __align__(16) short Ag[4096], Au[4096], Pt[4096];
  __shared__ __align__(16) short Bg[2][4096], Bu[2][4096], Bd[2][4096];
  int tid = threadIdx.x, lane = tid & 63, ms = (tid >> 6) * 16;
  int lm = lane & 15, lq = (lane >> 4) * 4;
  int cc0 = kz * (DFF_ / DKZ_);
  const unsigned short* Bgsrc = uoutT_g + (size_t)g * DFF_ * R_;
  const unsigned short* Busrc = uoutT_u + (size_t)g * DFF_ * R_;
  const unsigned short* Bdsrc = uinT_d + (size_t)g * 64 * 1024;
  for (int tile = blockIdx.x; tile < ntiles; tile += gridDim.x) {
    int pbase = p0 + tile * 64;
    int rv = pend - pbase; if (rv > 64) rv = 64;
    gstage_clamp_swz(Ag, xgb + (size_t)pbase * R_, R_, rv, tid);
    gstage_clamp_swz(Au, xub + (size_t)pbase * R_, R_, rv, tid);
    gstage_swz(Bg[0], Bgsrc + (size_t)cc0 * R_, R_, tid);
    gstage_swz(Bu[0], Busrc + (size_t)cc0 * R_, R_, tid);
    gstage_swz(Bd[0], Bdsrc + cc0, 1024, tid);
    __syncthreads();
    f32x4 accd[4] = {};
    int cur = 0;
#pragma unroll 1
    for (int c4 = 0; c4 < 4; ++c4) {
      if (c4 < 3) {
        int cc = cc0 + (c4 + 1) * 64;
        gstage_swz(Bg[cur ^ 1], Bgsrc + (size_t)cc * R_, R_, tid);
        gstage_swz(Bu[cur ^ 1], Busrc + (size_t)cc * R_, R_, tid);
        gstage_swz(Bd[cur ^ 1], Bdsrc + cc, 1024, tid);
      }
      f32x4 accg[4] = {}, accu[4] = {};
      mma_strip_swz(Ag, Bg[cur], ms, lane, accg);
      mma_strip_swz(Au, Bu[cur], ms, lane, accu);
#pragma unroll
      for (int nt = 0; nt < 4; ++nt)
#pragma unroll
        for (int r = 0; r < 4; ++r) {
          float gv = accg[nt][r];
          float av = gv / (1.f + expf(-gv)) * accu[nt][r];
          int prow = ms + lq + r;
          int pch = (nt << 1) + (lm >> 3);
          Pt[prow * 64 + ((pch ^ (prow & 7)) << 3) + (lm & 7)] = (short)f2bf(av);
        }
      mma_strip_swz(Pt, Bd[cur], ms, lane, accd);  // reads only own-wave rows of Pt
      __syncthreads();
      cur ^= 1;
    }
#pragma unroll
    for (int nt = 0; nt < 4; ++nt)
#pragma unroll
      for (int r = 0; r < 4; ++r) {
        int p = pbase + ms + lq + r;
        if (p < pend) xdp[((size_t)kz * F_ + p) * R_ + nt * 16 + lm] = accd[nt][r];
      }
    __syncthreads();
  }
}

// ---------------------------------------------------------------- D5: per-expert fold xdp + down core + wsm -> atomic Y
__global__ __launch_bounds__(256) void k_down_core(const float* __restrict__ xdp,
                                                   const float* __restrict__ core_d,
                                                   const int* __restrict__ bucket,
                                                   const float* __restrict__ wsm,
                                                   const int* __restrict__ off,
                                                   float* __restrict__ Yf) {
  int e = blockIdx.x >> 1, half = blockIdx.x & 1;
  int g = e >> 5;
  __shared__ float cd[4096];
  __shared__ float xs[4][64];
  int tid = threadIdx.x;
  for (int i = tid; i < 1024; i += 256)
    *(float4*)&cd[i * 4] = *(const float4*)&core_d[(size_t)e * 4096 + (size_t)i * 4];
  int p0 = off[e], n = off[e + 1] - p0;
  if (n < 0) n = 0;
  if (n > 1024) n = 1024;
  int hn = (n + 1) >> 1;
  int i0 = half * hn;
  int i1 = i0 + hn; if (i1 > n) i1 = n;
  int pl = tid >> 6, o = tid & 63;
  __syncthreads();
  for (int ib = i0; ib < i1; ib += 4) {
    int i = ib + pl;
    bool valid = i < i1;
    int p = p0 + i;
    int f = valid ? bucket[e * 1024 + i] : 0;
    float s = 0.f;
    if (valid) {
#pragma unroll
      for (int kz = 0; kz < DKZ_; ++kz) s += xdp[((size_t)kz * F_ + p) * R_ + o];
    }
    __syncthreads();
    xs[pl][o] = s;
    __syncthreads();
    if (valid) {
      float a = 0.f;
#pragma unroll 8
      for (int r = 0; r < R_; ++r) a = fmaf(xs[pl][r], cd[r * R_ + o], a);
      atomicAdd(&Yf[(size_t)(f >> 3) * 512 + g * 64 + o], wsm[f] * a);
    }
  }
}

// ---------------------------------------------------------------- D6: out = Y[1024,512] @ Uod2[512,1024] (2-phase, T14 A-split, swz)
__global__ __launch_bounds__(256) void k_fin(const float* __restrict__ Yf,
                                             const unsigned short* __restrict__ Uod2T,
                                             float* __restrict__ out) {
  int t0 = blockIdx.x * 64;
  int d0 = blockIdx.y * 64;
  __shared__ __align__(16) short sh[4][4096];  // A0 A1 B0 B1; Os overlays after loop
  int tid = threadIdx.x, lane = tid & 63, ms = (tid >> 6) * 16;
  int lm = lane & 15, lq = (lane >> 4) * 4;
  const float* Asrc = Yf + (size_t)t0 * 512;
  const unsigned short* Bsrc = Uod2T + (size_t)d0 * 512;
  f32x4 acc[4] = {};
  {
    float4 pre[4];
    a_load(pre, Asrc, 512, tid);
    a_write_swz(sh[0], pre, tid);
  }
  gstage_swz(sh[2], Bsrc, 512, tid);
  __syncthreads();
  int cur = 0;
#pragma unroll 1
  for (int i = 0; i < 8; ++i) {
    float4 pre[4];
    bool hp = i < 7;
    if (hp) {
      int kc = (i + 1) * 64;
      a_load(pre, Asrc + kc, 512, tid);          // f32 loads issue early
      gstage_swz(sh[2 + (cur ^ 1)], Bsrc + kc, 512, tid);
    }
    mma_strip_swz(sh[cur], sh[2 + cur], ms, lane, acc);
    if (hp) a_write_swz(sh[cur ^ 1], pre, tid);  // cvt+ds_write after MFMA
    __syncthreads();
    cur ^= 1;
  }
  float* Os = (float*)sh;  // 64x68 fp32 = 17.4 KB <= 32 KB
#pragma unroll
  for (int nt = 0; nt < 4; ++nt)
#pragma unroll
    for (int r = 0; r < 4; ++r)
      Os[(ms + lq + r) * 68 + nt * 16 + lm] = acc[nt][r];
  __syncthreads();
  for (int idx = tid; idx < 1024; idx += 256) {
    int r = idx >> 4, c4 = (idx & 15) << 2;
    *(float4*)&out[(size_t)(t0 + r) * D_ + d0 + c4] = *(const float4*)&Os[r * 68 + c4];
  }
}

// ================================================================ launch
extern "C" void kernel_launch(void* const* d_in, const int* in_sizes, int n_in,
                              void* d_out, int out_size, void* d_ws, size_t ws_size,
                              hipStream_t stream) {
  const float* x = (const float*)d_in[0];
  const float* Wg = (const float*)d_in[1];
  const float* uin_gate = (const float*)d_in[2];
  const float* core_gate = (const float*)d_in[3];
  const float* uout_gate = (const float*)d_in[4];
  const float* uin_up = (const float*)d_in[5];
  const float* core_up = (const float*)d_in[6];
  const float* uout_up = (const float*)d_in[7];
  const float* uin_down = (const float*)d_in[8];
  const float* core_down = (const float*)d_in[9];
  const float* uout_down = (const float*)d_in[10];
  float* out = (float*)d_out;

  char* ws = (char*)d_ws;
  size_t o = 0;
  auto alloc = [&](size_t bytes) { size_t r = o; o = (o + bytes + 255) & ~(size_t)255; return r; };
  size_t o_lp = alloc((size_t)LKZ_ * T_ * NEXP_ * 4);           // 4 MB
  size_t o_wsm = alloc(F_ * 4);
  size_t o_bucket = alloc((size_t)NEXP_ * 1024 * 4);            // 1 MB
  size_t o_cnt = alloc(NEXP_ * 4);
  size_t o_tickets = alloc(256);
  size_t o_off = alloc((NEXP_ + 1) * 4);
  size_t o_xb = alloc((size_t)T_ * D_ * 2);                     // 2 MB
  size_t o_uinT_g = alloc((size_t)G_ * 64 * 1024 * 2);          // 1 MB each
  size_t o_uinT_u = alloc((size_t)G_ * 64 * 1024 * 2);
  size_t o_uinT_d = alloc((size_t)G_ * 64 * 1024 * 2);
  size_t o_uoutT_g = alloc((size_t)G_ * 1024 * 64 * 2);
  size_t o_uoutT_u = alloc((size_t)G_ * 1024 * 64 * 2);
  size_t o_Uod2T = alloc((size_t)D_ * 512 * 2);                 // 1 MB
  size_t o_xgb = alloc((size_t)F_ * R_ * 2);                    // 1 MB
  size_t o_xub = alloc((size_t)F_ * R_ * 2);
  size_t o_Y = alloc((size_t)T_ * 512 * 4);                     // 2 MB fp32
  size_t o_pgp = alloc((size_t)PKZ_ * G_ * T_ * R_ * 4);        // 4 MB
  size_t o_pup = alloc((size_t)PKZ_ * G_ * T_ * R_ * 4);        // 4 MB
  size_t o_xdp = alloc((size_t)DKZ_ * F_ * R_ * 4);             // 8 MB
  (void)ws_size;

  float* lp = (float*)(ws + o_lp);
  float* wsm = (float*)(ws + o_wsm);
  int* bucket = (int*)(ws + o_bucket);
  int* cnt = (int*)(ws + o_cnt);
  int* tickets = (int*)(ws + o_tickets);
  int* off = (int*)(ws + o_off);
  unsigned short* xb = (unsigned short*)(ws + o_xb);
  unsigned short* uinT_g = (unsigned short*)(ws + o_uinT_g);
  unsigned short* uinT_u = (unsigned short*)(ws + o_uinT_u);
  unsigned short* uinT_d = (unsigned short*)(ws + o_uinT_d);
  unsigned short* uoutT_g = (unsigned short*)(ws + o_uoutT_g);
  unsigned short* uoutT_u = (unsigned short*)(ws + o_uoutT_u);
  unsigned short* Uod2T = (unsigned short*)(ws + o_Uod2T);
  unsigned short* xgb = (unsigned short*)(ws + o_xgb);
  unsigned short* xub = (unsigned short*)(ws + o_xub);
  float* Yf = (float*)(ws + o_Y);
  float* pgp = (float*)(ws + o_pgp);
  float* pup = (float*)(ws + o_pup);
  float* xdp = (float*)(ws + o_xdp);

  k_prep_logits<<<1408, 256, 0, stream>>>(x, Wg, uin_gate, uin_up, uin_down,
                                          uout_gate, uout_up, uout_down, xb,
                                          uinT_g, uinT_u, uinT_d,
                                          uoutT_g, uoutT_u, Uod2T,
                                          cnt, tickets, Yf, lp);
  k_pre<<<512, 256, 0, stream>>>(xb, uinT_g, uinT_u, pgp, pup);
  k_topk<<<256, 256, 0, stream>>>(lp, wsm, bucket, cnt, tickets, off);
  k_core_gu<<<NEXP_ * 2, 256, 0, stream>>>(pgp, pup, core_gate, core_up, bucket, off, xgb, xub);
  k_fused_ad<<<dim3(16, G_, DKZ_), 256, 0, stream>>>(xgb, xub, uoutT_g, uoutT_u, uinT_d, off, xdp);
  k_down_core<<<NEXP_ * 2, 256, 0, stream>>>(xdp, core_down, bucket, wsm, off, Yf);
  k_fin<<<dim3(16, 16), 256, 0, stream>>>(Yf, Uod2T, out);
}